// Round 2
// baseline (2151.189 us; speedup 1.0000x reference)
//
#include <hip/hip_runtime.h>

#define NN 100000
#define NE 1600000
#define DD 128
#define NG 512
#define ZCOLS 384
#define TM 32

// ---------------- CSR build (counting sort by dst) ----------------
__global__ __launch_bounds__(256) void k_hist(const int* __restrict__ dst, int* __restrict__ cnt) {
    for (int e = blockIdx.x * blockDim.x + threadIdx.x; e < NE; e += gridDim.x * blockDim.x)
        atomicAdd(&cnt[dst[e]], 1);
}

__global__ __launch_bounds__(1024) void k_scan(const int* __restrict__ cnt, int* __restrict__ off,
                                               int* __restrict__ cur) {
    __shared__ int s[1024];
    const int t = threadIdx.x;
    const int CH = (NN + 1023) / 1024;  // 98
    const int base = t * CH;
    int loc = 0;
    for (int i = 0; i < CH; i++) { int idx = base + i; if (idx < NN) loc += cnt[idx]; }
    s[t] = loc;
    __syncthreads();
    for (int st = 1; st < 1024; st <<= 1) {
        int v = (t >= st) ? s[t - st] : 0;
        __syncthreads();
        s[t] += v;
        __syncthreads();
    }
    int run = s[t] - loc;  // exclusive prefix
    for (int i = 0; i < CH; i++) {
        int idx = base + i;
        if (idx < NN) { off[idx] = run; cur[idx] = run; run += cnt[idx]; }
    }
    if (t == 1023) off[NN] = s[1023];
}

__global__ __launch_bounds__(256) void k_scatter(const int* __restrict__ src, const int* __restrict__ dst,
                                                 int* __restrict__ cur, int* __restrict__ ss) {
    for (int e = blockIdx.x * blockDim.x + threadIdx.x; e < NE; e += gridDim.x * blockDim.x) {
        int p = atomicAdd(&cur[dst[e]], 1);
        ss[p] = src[e];
    }
}

// ---------------- fused aggregate + MLP + BN-stats ----------------
__device__ __forceinline__ void tile_gemm(const float (*A)[DD + 4], const float* __restrict__ W,
                                          const float* __restrict__ bias, int r0, int c0,
                                          float acc[2][8]) {
    const float4 ba = *(const float4*)(bias + c0);
    const float4 bb = *(const float4*)(bias + c0 + 4);
#pragma unroll
    for (int i = 0; i < 2; i++) {
        acc[i][0] = ba.x; acc[i][1] = ba.y; acc[i][2] = ba.z; acc[i][3] = ba.w;
        acc[i][4] = bb.x; acc[i][5] = bb.y; acc[i][6] = bb.z; acc[i][7] = bb.w;
    }
    for (int k = 0; k < DD; k += 4) {
        float4 a0 = *(const float4*)&A[r0][k];
        float4 a1 = *(const float4*)&A[r0 + 1][k];
        float av0[4] = {a0.x, a0.y, a0.z, a0.w};
        float av1[4] = {a1.x, a1.y, a1.z, a1.w};
#pragma unroll
        for (int kk = 0; kk < 4; kk++) {
            const float* wr = W + (k + kk) * DD + c0;
            float4 wa = *(const float4*)wr;
            float4 wb = *(const float4*)(wr + 4);
            float w[8] = {wa.x, wa.y, wa.z, wa.w, wb.x, wb.y, wb.z, wb.w};
#pragma unroll
            for (int j = 0; j < 8; j++) {
                acc[0][j] = fmaf(av0[kk], w[j], acc[0][j]);
                acc[1][j] = fmaf(av1[kk], w[j], acc[1][j]);
            }
        }
    }
}

__global__ __launch_bounds__(256) void k_layer(
    const float* __restrict__ z, int zstride,
    const int* __restrict__ off, const int* __restrict__ ss,
    const float* __restrict__ W1, const float* __restrict__ b1,
    const float* __restrict__ W2, const float* __restrict__ b2,
    float* __restrict__ hout,  // d_out + l*128, row stride ZCOLS; raw h written here
    float* __restrict__ s1, float* __restrict__ s2) {
    __shared__ float agg[TM][DD + 4];
    __shared__ float h1[TM][DD + 4];
    const int tid = threadIdx.x;
    const int node0 = blockIdx.x * TM;

    // ---- gather: agg = z[i] + sum_{src in CSR[i]} z[src] ----
    const int wv = tid >> 6, ln = tid & 63;
    for (int r = wv * 8; r < wv * 8 + 8; ++r) {
        int i = node0 + r;
        float ax = 0.f, ay = 0.f;
        if (i < NN) {
            const float* zr = z + (size_t)i * zstride;
            float2 v0 = *(const float2*)(zr + 2 * ln);
            ax = v0.x; ay = v0.y;
            int e0 = off[i], e1 = off[i + 1];
            for (int k = e0; k < e1; ++k) {
                const float* sr = z + (size_t)ss[k] * zstride;
                float2 v = *(const float2*)(sr + 2 * ln);
                ax += v.x; ay += v.y;
            }
        }
        agg[r][2 * ln] = ax;
        agg[r][2 * ln + 1] = ay;
    }
    __syncthreads();

    const int tx = tid & 15, ty = tid >> 4;
    const int c0 = tx * 8, r0 = ty * 2;

    // ---- GEMM1 + ReLU -> h1 (LDS) ----
    float acc[2][8];
    tile_gemm(agg, W1, b1, r0, c0, acc);
#pragma unroll
    for (int i = 0; i < 2; i++)
#pragma unroll
        for (int j = 0; j < 8; j++) h1[r0 + i][c0 + j] = fmaxf(acc[i][j], 0.f);
    __syncthreads();

    // ---- GEMM2 -> raw h ----
    tile_gemm(h1, W2, b2, r0, c0, acc);

    // store raw h to d_out slice
#pragma unroll
    for (int i = 0; i < 2; i++) {
        int node = node0 + r0 + i;
        if (node < NN) {
            float* op = hout + (size_t)node * ZCOLS + c0;
            *(float4*)op = make_float4(acc[i][0], acc[i][1], acc[i][2], acc[i][3]);
            *(float4*)(op + 4) = make_float4(acc[i][4], acc[i][5], acc[i][6], acc[i][7]);
        }
    }

    // ---- per-block column sum / sumsq -> global atomics ----
    float sv[8], qv[8];
#pragma unroll
    for (int j = 0; j < 8; j++) { sv[j] = 0.f; qv[j] = 0.f; }
#pragma unroll
    for (int i = 0; i < 2; i++) {
        if (node0 + r0 + i < NN) {
#pragma unroll
            for (int j = 0; j < 8; j++) { float v = acc[i][j]; sv[j] += v; qv[j] += v * v; }
        }
    }
    float2* red = (float2*)&agg[0][0];  // [16][128] float2 = 16 KB, fits in agg
    __syncthreads();                    // everyone past GEMM1's agg reads & ready to reuse
#pragma unroll
    for (int j = 0; j < 8; j++) red[ty * DD + c0 + j] = make_float2(sv[j], qv[j]);
    __syncthreads();
    for (int st = 8; st >= 1; st >>= 1) {
        if (ty < st) {
#pragma unroll
            for (int j = 0; j < 8; j++) {
                float2 a = red[ty * DD + c0 + j];
                float2 b = red[(ty + st) * DD + c0 + j];
                red[ty * DD + c0 + j] = make_float2(a.x + b.x, a.y + b.y);
            }
        }
        __syncthreads();
    }
    if (tid < DD) {
        float2 v = red[tid];
        atomicAdd(&s1[tid], v.x);
        atomicAdd(&s2[tid], v.y);
    }
}

// ---------------- BN finalize + apply ----------------
__global__ void k_bnfin(const float* __restrict__ s1, const float* __restrict__ s2,
                        const float* __restrict__ gamma, const float* __restrict__ beta,
                        float* __restrict__ ab) {
    int c = threadIdx.x;  // 128
    float mean = s1[c] * (1.0f / NN);
    float var = s2[c] * (1.0f / NN) - mean * mean;
    float rstd = rsqrtf(var + 1e-5f);
    float a = gamma[c] * rstd;
    ab[c] = a;
    ab[DD + c] = beta[c] - mean * a;
}

__global__ __launch_bounds__(256) void k_bnapply(float* __restrict__ hout, const float* __restrict__ ab,
                                                 int relu) {
    int gid = blockIdx.x * blockDim.x + threadIdx.x;
    if (gid >= NN * 32) return;
    int i = gid >> 5, q = gid & 31;
    int c = q * 4;
    float4* p = (float4*)(hout + (size_t)i * ZCOLS + c);
    float4 v = *p;
    float4 A = *(const float4*)(ab + c);
    float4 B = *(const float4*)(ab + DD + c);
    v.x = v.x * A.x + B.x;
    v.y = v.y * A.y + B.y;
    v.z = v.z * A.z + B.z;
    v.w = v.w * A.w + B.w;
    if (relu) {
        v.x = fmaxf(v.x, 0.f); v.y = fmaxf(v.y, 0.f);
        v.z = fmaxf(v.z, 0.f); v.w = fmaxf(v.w, 0.f);
    }
    *p = v;
}

// ---------------- graph pooling (batch is sorted) ----------------
__global__ __launch_bounds__(256) void k_pool(const float* __restrict__ zc, const int* __restrict__ batch,
                                              float* __restrict__ g) {
    const int gr = blockIdx.x;
    int lo = 0, hi = NN;
    while (lo < hi) { int mid = (lo + hi) >> 1; if (batch[mid] < gr) lo = mid + 1; else hi = mid; }
    const int start = lo;
    hi = NN;
    while (lo < hi) { int mid = (lo + hi) >> 1; if (batch[mid] < gr + 1) lo = mid + 1; else hi = mid; }
    const int end = lo;

    const int tid = threadIdx.x;
    const int h = tid >> 7, c = tid & 127;
    float a0 = 0.f, a1 = 0.f, a2 = 0.f;
    for (int r = start + h; r < end; r += 2) {
        const float* row = zc + (size_t)r * ZCOLS;
        a0 += row[c];
        a1 += row[c + DD];
        a2 += row[c + 2 * DD];
    }
    __shared__ float red[3][256];
    red[0][tid] = a0; red[1][tid] = a1; red[2][tid] = a2;
    __syncthreads();
    if (tid < 128) {
        float* gp = g + (size_t)gr * ZCOLS;
        gp[c] = red[0][tid] + red[0][tid + 128];
        gp[c + DD] = red[1][tid] + red[1][tid + 128];
        gp[c + 2 * DD] = red[2][tid] + red[2][tid + 128];
    }
}

extern "C" void kernel_launch(void* const* d_in, const int* in_sizes, int n_in,
                              void* d_out, int out_size, void* d_ws, size_t ws_size,
                              hipStream_t stream) {
    const float* x = (const float*)d_in[0];
    const int* ei = (const int*)d_in[1];
    const int* batch = (const int*)d_in[2];
    const float* W1 = (const float*)d_in[3];
    const float* b1 = (const float*)d_in[4];
    const float* W2 = (const float*)d_in[5];
    const float* b2 = (const float*)d_in[6];
    const float* gamma = (const float*)d_in[7];
    const float* beta = (const float*)d_in[8];
    float* out = (float*)d_out;

    const int* esrc = ei;        // edge_index[0]
    const int* edst = ei + NE;   // edge_index[1]

    int* cnt = (int*)d_ws;          // N
    int* off = cnt + NN;            // N+1
    int* cur = off + NN + 1;        // N
    int* ss = cur + NN;             // E (sources sorted by dst)
    float* s1 = (float*)(ss + NE);  // 128
    float* s2 = s1 + DD;            // 128
    float* ab = s2 + DD;            // 256

    hipMemsetAsync(cnt, 0, NN * sizeof(int), stream);
    k_hist<<<2048, 256, 0, stream>>>(edst, cnt);
    k_scan<<<1, 1024, 0, stream>>>(cnt, off, cur);
    k_scatter<<<2048, 256, 0, stream>>>(esrc, edst, cur, ss);

    float* gout = out + (size_t)NN * ZCOLS;
    for (int l = 0; l < 3; l++) {
        hipMemsetAsync(s1, 0, 2 * DD * sizeof(float), stream);
        const float* z = (l == 0) ? x : out + (l - 1) * DD;
        int zs = (l == 0) ? DD : ZCOLS;
        k_layer<<<(NN + TM - 1) / TM, 256, 0, stream>>>(
            z, zs, off, ss, W1 + l * DD * DD, b1 + l * DD, W2 + l * DD * DD, b2 + l * DD,
            out + l * DD, s1, s2);
        k_bnfin<<<1, 128, 0, stream>>>(s1, s2, gamma + l * DD, beta + l * DD, ab);
        k_bnapply<<<(NN * 32 + 255) / 256, 256, 0, stream>>>(out + l * DD, ab, (l < 2) ? 1 : 0);
    }
    k_pool<<<NG, 256, 0, stream>>>(out, batch, gout);
}

// Round 3
// 1637.367 us; speedup vs baseline: 1.3138x; 1.3138x over previous
//
#include <hip/hip_runtime.h>

#define NN 100000
#define NE 1600000
#define DD 128
#define NG 512
#define ZCOLS 384
#define TM 32

// ---------------- CSR build (counting sort by dst) ----------------
__global__ __launch_bounds__(256) void k_hist(const int* __restrict__ dst, int* __restrict__ cnt) {
    for (int e = blockIdx.x * blockDim.x + threadIdx.x; e < NE; e += gridDim.x * blockDim.x)
        atomicAdd(&cnt[dst[e]], 1);
}

__global__ __launch_bounds__(1024) void k_scan(const int* __restrict__ cnt, int* __restrict__ off,
                                               int* __restrict__ cur) {
    __shared__ int s[1024];
    const int t = threadIdx.x;
    const int CH = (NN + 1023) / 1024;  // 98
    const int base = t * CH;
    int loc = 0;
    for (int i = 0; i < CH; i++) { int idx = base + i; if (idx < NN) loc += cnt[idx]; }
    s[t] = loc;
    __syncthreads();
    for (int st = 1; st < 1024; st <<= 1) {
        int v = (t >= st) ? s[t - st] : 0;
        __syncthreads();
        s[t] += v;
        __syncthreads();
    }
    int run = s[t] - loc;  // exclusive prefix
    for (int i = 0; i < CH; i++) {
        int idx = base + i;
        if (idx < NN) { off[idx] = run; cur[idx] = run; run += cnt[idx]; }
    }
    if (t == 1023) off[NN] = s[1023];
}

__global__ __launch_bounds__(256) void k_scatter(const int* __restrict__ src, const int* __restrict__ dst,
                                                 int* __restrict__ cur, int* __restrict__ ss) {
    for (int e = blockIdx.x * blockDim.x + threadIdx.x; e < NE; e += gridDim.x * blockDim.x) {
        int p = atomicAdd(&cur[dst[e]], 1);
        ss[p] = src[e];
    }
}

// ---------------- fused aggregate + MLP + BN-stats ----------------
__device__ __forceinline__ void tile_gemm(const float (*A)[DD + 4], const float* __restrict__ W,
                                          const float* __restrict__ bias, int r0, int c0,
                                          float acc[2][8]) {
    const float4 ba = *(const float4*)(bias + c0);
    const float4 bb = *(const float4*)(bias + c0 + 4);
#pragma unroll
    for (int i = 0; i < 2; i++) {
        acc[i][0] = ba.x; acc[i][1] = ba.y; acc[i][2] = ba.z; acc[i][3] = ba.w;
        acc[i][4] = bb.x; acc[i][5] = bb.y; acc[i][6] = bb.z; acc[i][7] = bb.w;
    }
    for (int k = 0; k < DD; k += 4) {
        float4 a0 = *(const float4*)&A[r0][k];
        float4 a1 = *(const float4*)&A[r0 + 1][k];
        float av0[4] = {a0.x, a0.y, a0.z, a0.w};
        float av1[4] = {a1.x, a1.y, a1.z, a1.w};
#pragma unroll
        for (int kk = 0; kk < 4; kk++) {
            const float* wr = W + (k + kk) * DD + c0;
            float4 wa = *(const float4*)wr;
            float4 wb = *(const float4*)(wr + 4);
            float w[8] = {wa.x, wa.y, wa.z, wa.w, wb.x, wb.y, wb.z, wb.w};
#pragma unroll
            for (int j = 0; j < 8; j++) {
                acc[0][j] = fmaf(av0[kk], w[j], acc[0][j]);
                acc[1][j] = fmaf(av1[kk], w[j], acc[1][j]);
            }
        }
    }
}

// Single LDS buffer reused for: gather(agg) -> h1 -> BN reduction.
// LDS 16.9 KB -> 8 blocks/CU (vs 2-buffer 33.8 KB -> 4 blocks/CU).
__global__ __launch_bounds__(256) void k_layer(
    const float* __restrict__ z, int zstride,
    const int* __restrict__ off, const int* __restrict__ ss,
    const float* __restrict__ W1, const float* __restrict__ b1,
    const float* __restrict__ W2, const float* __restrict__ b2,
    float* __restrict__ hout,  // d_out + l*128, row stride ZCOLS; raw h written here
    float* __restrict__ s1, float* __restrict__ s2) {
    __shared__ float buf[TM][DD + 4];
    const int tid = threadIdx.x;
    const int node0 = blockIdx.x * TM;

    // ---- gather: buf = z[i] + sum_{src in CSR[i]} z[src] ----
    // Edge loop unrolled x4 with index preload: 4 independent row loads in flight.
    const int wv = tid >> 6, ln = tid & 63;
    for (int r = wv * 8; r < wv * 8 + 8; ++r) {
        int i = node0 + r;
        float ax = 0.f, ay = 0.f;
        if (i < NN) {
            const float* zr = z + (size_t)i * zstride + 2 * ln;
            float2 v0 = *(const float2*)zr;
            ax = v0.x; ay = v0.y;
            const int e0 = off[i], e1 = off[i + 1];
            int k = e0;
            for (; k + 4 <= e1; k += 4) {
                int i0 = ss[k], i1 = ss[k + 1], i2 = ss[k + 2], i3 = ss[k + 3];
                float2 va = *(const float2*)(z + (size_t)i0 * zstride + 2 * ln);
                float2 vb = *(const float2*)(z + (size_t)i1 * zstride + 2 * ln);
                float2 vc = *(const float2*)(z + (size_t)i2 * zstride + 2 * ln);
                float2 vd = *(const float2*)(z + (size_t)i3 * zstride + 2 * ln);
                ax += va.x; ay += va.y;
                ax += vb.x; ay += vb.y;
                ax += vc.x; ay += vc.y;
                ax += vd.x; ay += vd.y;
            }
            for (; k < e1; ++k) {
                float2 v = *(const float2*)(z + (size_t)ss[k] * zstride + 2 * ln);
                ax += v.x; ay += v.y;
            }
        }
        buf[r][2 * ln] = ax;
        buf[r][2 * ln + 1] = ay;
    }
    __syncthreads();

    const int tx = tid & 15, ty = tid >> 4;
    const int c0 = tx * 8, r0 = ty * 2;

    // ---- GEMM1 + ReLU -> registers ----
    float acc[2][8];
    tile_gemm(buf, W1, b1, r0, c0, acc);
    float r1[2][8];
#pragma unroll
    for (int i = 0; i < 2; i++)
#pragma unroll
        for (int j = 0; j < 8; j++) r1[i][j] = fmaxf(acc[i][j], 0.f);
    __syncthreads();  // everyone done reading buf(agg)

    // write h1 into the same buffer
#pragma unroll
    for (int i = 0; i < 2; i++)
#pragma unroll
        for (int j = 0; j < 8; j++) buf[r0 + i][c0 + j] = r1[i][j];
    __syncthreads();

    // ---- GEMM2 -> raw h ----
    tile_gemm(buf, W2, b2, r0, c0, acc);

    // store raw h to d_out slice
#pragma unroll
    for (int i = 0; i < 2; i++) {
        int node = node0 + r0 + i;
        if (node < NN) {
            float* op = hout + (size_t)node * ZCOLS + c0;
            *(float4*)op = make_float4(acc[i][0], acc[i][1], acc[i][2], acc[i][3]);
            *(float4*)(op + 4) = make_float4(acc[i][4], acc[i][5], acc[i][6], acc[i][7]);
        }
    }

    // ---- per-block column sum / sumsq -> global atomics ----
    float sv[8], qv[8];
#pragma unroll
    for (int j = 0; j < 8; j++) { sv[j] = 0.f; qv[j] = 0.f; }
#pragma unroll
    for (int i = 0; i < 2; i++) {
        if (node0 + r0 + i < NN) {
#pragma unroll
            for (int j = 0; j < 8; j++) { float v = acc[i][j]; sv[j] += v; qv[j] += v * v; }
        }
    }
    float2* red = (float2*)&buf[0][0];  // [16][128] float2 = 16 KB, fits
    __syncthreads();                    // everyone done reading buf(h1)
#pragma unroll
    for (int j = 0; j < 8; j++) red[ty * DD + c0 + j] = make_float2(sv[j], qv[j]);
    __syncthreads();
    for (int st = 8; st >= 1; st >>= 1) {
        if (ty < st) {
#pragma unroll
            for (int j = 0; j < 8; j++) {
                float2 a = red[ty * DD + c0 + j];
                float2 b = red[(ty + st) * DD + c0 + j];
                red[ty * DD + c0 + j] = make_float2(a.x + b.x, a.y + b.y);
            }
        }
        __syncthreads();
    }
    if (tid < DD) {
        float2 v = red[tid];
        atomicAdd(&s1[tid], v.x);
        atomicAdd(&s2[tid], v.y);
    }
}

// ---------------- BN finalize + apply ----------------
__global__ void k_bnfin(const float* __restrict__ s1, const float* __restrict__ s2,
                        const float* __restrict__ gamma, const float* __restrict__ beta,
                        float* __restrict__ ab) {
    int c = threadIdx.x;  // 128
    float mean = s1[c] * (1.0f / NN);
    float var = s2[c] * (1.0f / NN) - mean * mean;
    float rstd = rsqrtf(var + 1e-5f);
    float a = gamma[c] * rstd;
    ab[c] = a;
    ab[DD + c] = beta[c] - mean * a;
}

__global__ __launch_bounds__(256) void k_bnapply(float* __restrict__ hout, const float* __restrict__ ab,
                                                 int relu) {
    int gid = blockIdx.x * blockDim.x + threadIdx.x;
    if (gid >= NN * 32) return;
    int i = gid >> 5, q = gid & 31;
    int c = q * 4;
    float4* p = (float4*)(hout + (size_t)i * ZCOLS + c);
    float4 v = *p;
    float4 A = *(const float4*)(ab + c);
    float4 B = *(const float4*)(ab + DD + c);
    v.x = v.x * A.x + B.x;
    v.y = v.y * A.y + B.y;
    v.z = v.z * A.z + B.z;
    v.w = v.w * A.w + B.w;
    if (relu) {
        v.x = fmaxf(v.x, 0.f); v.y = fmaxf(v.y, 0.f);
        v.z = fmaxf(v.z, 0.f); v.w = fmaxf(v.w, 0.f);
    }
    *p = v;
}

// ---------------- graph pooling (batch is sorted) ----------------
__global__ __launch_bounds__(256) void k_pool(const float* __restrict__ zc, const int* __restrict__ batch,
                                              float* __restrict__ g) {
    const int gr = blockIdx.x;
    int lo = 0, hi = NN;
    while (lo < hi) { int mid = (lo + hi) >> 1; if (batch[mid] < gr) lo = mid + 1; else hi = mid; }
    const int start = lo;
    hi = NN;
    while (lo < hi) { int mid = (lo + hi) >> 1; if (batch[mid] < gr + 1) lo = mid + 1; else hi = mid; }
    const int end = lo;

    const int tid = threadIdx.x;
    const int h = tid >> 7, c = tid & 127;
    float a0 = 0.f, a1 = 0.f, a2 = 0.f;
    for (int r = start + h; r < end; r += 2) {
        const float* row = zc + (size_t)r * ZCOLS;
        a0 += row[c];
        a1 += row[c + DD];
        a2 += row[c + 2 * DD];
    }
    __shared__ float red[3][256];
    red[0][tid] = a0; red[1][tid] = a1; red[2][tid] = a2;
    __syncthreads();
    if (tid < 128) {
        float* gp = g + (size_t)gr * ZCOLS;
        gp[c] = red[0][tid] + red[0][tid + 128];
        gp[c + DD] = red[1][tid] + red[1][tid + 128];
        gp[c + 2 * DD] = red[2][tid] + red[2][tid + 128];
    }
}

extern "C" void kernel_launch(void* const* d_in, const int* in_sizes, int n_in,
                              void* d_out, int out_size, void* d_ws, size_t ws_size,
                              hipStream_t stream) {
    const float* x = (const float*)d_in[0];
    const int* ei = (const int*)d_in[1];
    const int* batch = (const int*)d_in[2];
    const float* W1 = (const float*)d_in[3];
    const float* b1 = (const float*)d_in[4];
    const float* W2 = (const float*)d_in[5];
    const float* b2 = (const float*)d_in[6];
    const float* gamma = (const float*)d_in[7];
    const float* beta = (const float*)d_in[8];
    float* out = (float*)d_out;

    const int* esrc = ei;        // edge_index[0]
    const int* edst = ei + NE;   // edge_index[1]

    int* cnt = (int*)d_ws;          // N
    int* off = cnt + NN;            // N+1
    int* cur = off + NN + 1;        // N
    int* ss = cur + NN;             // E (sources sorted by dst)
    float* s1 = (float*)(ss + NE);  // 128
    float* s2 = s1 + DD;            // 128
    float* ab = s2 + DD;            // 256

    hipMemsetAsync(cnt, 0, NN * sizeof(int), stream);
    k_hist<<<2048, 256, 0, stream>>>(edst, cnt);
    k_scan<<<1, 1024, 0, stream>>>(cnt, off, cur);
    k_scatter<<<2048, 256, 0, stream>>>(esrc, edst, cur, ss);

    float* gout = out + (size_t)NN * ZCOLS;
    for (int l = 0; l < 3; l++) {
        hipMemsetAsync(s1, 0, 2 * DD * sizeof(float), stream);
        const float* z = (l == 0) ? x : out + (l - 1) * DD;
        int zs = (l == 0) ? DD : ZCOLS;
        k_layer<<<(NN + TM - 1) / TM, 256, 0, stream>>>(
            z, zs, off, ss, W1 + l * DD * DD, b1 + l * DD, W2 + l * DD * DD, b2 + l * DD,
            out + l * DD, s1, s2);
        k_bnfin<<<1, 128, 0, stream>>>(s1, s2, gamma + l * DD, beta + l * DD, ab);
        k_bnapply<<<(NN * 32 + 255) / 256, 256, 0, stream>>>(out + l * DD, ab, (l < 2) ? 1 : 0);
    }
    k_pool<<<NG, 256, 0, stream>>>(out, batch, gout);
}

// Round 4
// 1533.176 us; speedup vs baseline: 1.4031x; 1.0680x over previous
//
#include <hip/hip_runtime.h>

#define NN 100000
#define NE 1600000
#define DD 128
#define NG 512
#define ZCOLS 384
#define TM 32

// ---------------- CSR build (counting sort by dst) ----------------
__global__ __launch_bounds__(256) void k_hist(const int* __restrict__ dst, int* __restrict__ cnt) {
    for (int e = blockIdx.x * blockDim.x + threadIdx.x; e < NE; e += gridDim.x * blockDim.x)
        atomicAdd(&cnt[dst[e]], 1);
}

__global__ __launch_bounds__(1024) void k_scan(const int* __restrict__ cnt, int* __restrict__ off,
                                               int* __restrict__ cur) {
    __shared__ int s[1024];
    const int t = threadIdx.x;
    const int CH = (NN + 1023) / 1024;  // 98
    const int base = t * CH;
    int loc = 0;
    for (int i = 0; i < CH; i++) { int idx = base + i; if (idx < NN) loc += cnt[idx]; }
    s[t] = loc;
    __syncthreads();
    for (int st = 1; st < 1024; st <<= 1) {
        int v = (t >= st) ? s[t - st] : 0;
        __syncthreads();
        s[t] += v;
        __syncthreads();
    }
    int run = s[t] - loc;  // exclusive prefix
    for (int i = 0; i < CH; i++) {
        int idx = base + i;
        if (idx < NN) { off[idx] = run; cur[idx] = run; run += cnt[idx]; }
    }
    if (t == 1023) off[NN] = s[1023];
}

__global__ __launch_bounds__(256) void k_scatter(const int* __restrict__ src, const int* __restrict__ dst,
                                                 int* __restrict__ cur, int* __restrict__ ss) {
    for (int e = blockIdx.x * blockDim.x + threadIdx.x; e < NE; e += gridDim.x * blockDim.x) {
        int p = atomicAdd(&cur[dst[e]], 1);
        ss[p] = src[e];
    }
}

// ---------------- bf16 helpers ----------------
__device__ __forceinline__ float bf_lo(unsigned u) { return __uint_as_float(u << 16); }
__device__ __forceinline__ float bf_hi(unsigned u) { return __uint_as_float(u & 0xFFFF0000u); }
__device__ __forceinline__ unsigned pack_bf16(float a, float b) {
    unsigned ua = __float_as_uint(a), ub = __float_as_uint(b);
    ua = (ua + 0x7FFFu + ((ua >> 16) & 1u)) >> 16;
    ub = (ub + 0x7FFFu + ((ub >> 16) & 1u)) >> 16;
    return (ub << 16) | ua;
}

// x (fp32 [NN][128]) -> packed bf16 [NN][64 uints]
__global__ __launch_bounds__(256) void k_xcast(const float* __restrict__ x, unsigned* __restrict__ xb) {
    int gid = blockIdx.x * blockDim.x + threadIdx.x;
    if (gid >= NN * 64) return;
    int i = gid >> 6, ln = gid & 63;
    float2 v = *(const float2*)(x + (size_t)i * DD + 2 * ln);
    xb[gid] = pack_bf16(v.x, v.y);
}

// ---------------- fused aggregate + MLP + BN-stats ----------------
__device__ __forceinline__ void tile_gemm(const float (*A)[DD + 4], const float* __restrict__ W,
                                          const float* __restrict__ bias, int r0, int c0,
                                          float acc[2][8]) {
    const float4 ba = *(const float4*)(bias + c0);
    const float4 bb = *(const float4*)(bias + c0 + 4);
#pragma unroll
    for (int i = 0; i < 2; i++) {
        acc[i][0] = ba.x; acc[i][1] = ba.y; acc[i][2] = ba.z; acc[i][3] = ba.w;
        acc[i][4] = bb.x; acc[i][5] = bb.y; acc[i][6] = bb.z; acc[i][7] = bb.w;
    }
    for (int k = 0; k < DD; k += 4) {
        float4 a0 = *(const float4*)&A[r0][k];
        float4 a1 = *(const float4*)&A[r0 + 1][k];
        float av0[4] = {a0.x, a0.y, a0.z, a0.w};
        float av1[4] = {a1.x, a1.y, a1.z, a1.w};
#pragma unroll
        for (int kk = 0; kk < 4; kk++) {
            const float* wr = W + (k + kk) * DD + c0;
            float4 wa = *(const float4*)wr;
            float4 wb = *(const float4*)(wr + 4);
            float w[8] = {wa.x, wa.y, wa.z, wa.w, wb.x, wb.y, wb.z, wb.w};
#pragma unroll
            for (int j = 0; j < 8; j++) {
                acc[0][j] = fmaf(av0[kk], w[j], acc[0][j]);
                acc[1][j] = fmaf(av1[kk], w[j], acc[1][j]);
            }
        }
    }
}

// Single LDS buffer reused for: gather(agg) -> h1 -> BN reduction. 16.9 KB.
// Gather reads packed-bf16 z (4 B/lane/row) when zb != nullptr; fp32 fallback otherwise.
__global__ __launch_bounds__(256) void k_layer(
    const unsigned* __restrict__ zb, const float* __restrict__ zf, int zstride,
    const int* __restrict__ off, const int* __restrict__ ss,
    const float* __restrict__ W1, const float* __restrict__ b1,
    const float* __restrict__ W2, const float* __restrict__ b2,
    float* __restrict__ hout,  // d_out + l*128, row stride ZCOLS; raw h written here
    float* __restrict__ s1, float* __restrict__ s2) {
    __shared__ float buf[TM][DD + 4];
    const int tid = threadIdx.x;
    const int node0 = blockIdx.x * TM;

    const int wv = tid >> 6, ln = tid & 63;
    if (zb) {
        // ---- bf16 gather, 8-deep edge unroll: 8 independent 4B row loads in flight ----
        for (int r = wv * 8; r < wv * 8 + 8; ++r) {
            int i = node0 + r;
            float ax = 0.f, ay = 0.f;
            if (i < NN) {
                unsigned u = zb[(size_t)i * 64 + ln];
                ax = bf_lo(u); ay = bf_hi(u);
                const int e0 = off[i], e1 = off[i + 1];
                int k = e0;
                for (; k + 8 <= e1; k += 8) {
                    int i0 = ss[k], i1 = ss[k + 1], i2 = ss[k + 2], i3 = ss[k + 3];
                    int i4 = ss[k + 4], i5 = ss[k + 5], i6 = ss[k + 6], i7 = ss[k + 7];
                    unsigned u0 = zb[(size_t)i0 * 64 + ln], u1 = zb[(size_t)i1 * 64 + ln];
                    unsigned u2 = zb[(size_t)i2 * 64 + ln], u3 = zb[(size_t)i3 * 64 + ln];
                    unsigned u4 = zb[(size_t)i4 * 64 + ln], u5 = zb[(size_t)i5 * 64 + ln];
                    unsigned u6 = zb[(size_t)i6 * 64 + ln], u7 = zb[(size_t)i7 * 64 + ln];
                    ax += bf_lo(u0) + bf_lo(u1) + bf_lo(u2) + bf_lo(u3)
                        + bf_lo(u4) + bf_lo(u5) + bf_lo(u6) + bf_lo(u7);
                    ay += bf_hi(u0) + bf_hi(u1) + bf_hi(u2) + bf_hi(u3)
                        + bf_hi(u4) + bf_hi(u5) + bf_hi(u6) + bf_hi(u7);
                }
                for (; k < e1; ++k) {
                    unsigned uu = zb[(size_t)ss[k] * 64 + ln];
                    ax += bf_lo(uu); ay += bf_hi(uu);
                }
            }
            buf[r][2 * ln] = ax;
            buf[r][2 * ln + 1] = ay;
        }
    } else {
        // ---- fp32 fallback gather (4-deep unroll) ----
        for (int r = wv * 8; r < wv * 8 + 8; ++r) {
            int i = node0 + r;
            float ax = 0.f, ay = 0.f;
            if (i < NN) {
                float2 v0 = *(const float2*)(zf + (size_t)i * zstride + 2 * ln);
                ax = v0.x; ay = v0.y;
                const int e0 = off[i], e1 = off[i + 1];
                int k = e0;
                for (; k + 4 <= e1; k += 4) {
                    int i0 = ss[k], i1 = ss[k + 1], i2 = ss[k + 2], i3 = ss[k + 3];
                    float2 va = *(const float2*)(zf + (size_t)i0 * zstride + 2 * ln);
                    float2 vb = *(const float2*)(zf + (size_t)i1 * zstride + 2 * ln);
                    float2 vc = *(const float2*)(zf + (size_t)i2 * zstride + 2 * ln);
                    float2 vd = *(const float2*)(zf + (size_t)i3 * zstride + 2 * ln);
                    ax += va.x + vb.x + vc.x + vd.x;
                    ay += va.y + vb.y + vc.y + vd.y;
                }
                for (; k < e1; ++k) {
                    float2 v = *(const float2*)(zf + (size_t)ss[k] * zstride + 2 * ln);
                    ax += v.x; ay += v.y;
                }
            }
            buf[r][2 * ln] = ax;
            buf[r][2 * ln + 1] = ay;
        }
    }
    __syncthreads();

    const int tx = tid & 15, ty = tid >> 4;
    const int c0 = tx * 8, r0 = ty * 2;

    // ---- GEMM1 + ReLU ----
    float acc[2][8];
    tile_gemm(buf, W1, b1, r0, c0, acc);
    float r1[2][8];
#pragma unroll
    for (int i = 0; i < 2; i++)
#pragma unroll
        for (int j = 0; j < 8; j++) r1[i][j] = fmaxf(acc[i][j], 0.f);
    __syncthreads();  // done reading buf(agg)
#pragma unroll
    for (int i = 0; i < 2; i++)
#pragma unroll
        for (int j = 0; j < 8; j++) buf[r0 + i][c0 + j] = r1[i][j];
    __syncthreads();

    // ---- GEMM2 -> raw h ----
    tile_gemm(buf, W2, b2, r0, c0, acc);

#pragma unroll
    for (int i = 0; i < 2; i++) {
        int node = node0 + r0 + i;
        if (node < NN) {
            float* op = hout + (size_t)node * ZCOLS + c0;
            *(float4*)op = make_float4(acc[i][0], acc[i][1], acc[i][2], acc[i][3]);
            *(float4*)(op + 4) = make_float4(acc[i][4], acc[i][5], acc[i][6], acc[i][7]);
        }
    }

    // ---- per-block column sum / sumsq -> global atomics ----
    float sv[8], qv[8];
#pragma unroll
    for (int j = 0; j < 8; j++) { sv[j] = 0.f; qv[j] = 0.f; }
#pragma unroll
    for (int i = 0; i < 2; i++) {
        if (node0 + r0 + i < NN) {
#pragma unroll
            for (int j = 0; j < 8; j++) { float v = acc[i][j]; sv[j] += v; qv[j] += v * v; }
        }
    }
    float2* red = (float2*)&buf[0][0];  // 16 KB, fits
    __syncthreads();                    // done reading buf(h1)
#pragma unroll
    for (int j = 0; j < 8; j++) red[ty * DD + c0 + j] = make_float2(sv[j], qv[j]);
    __syncthreads();
    for (int st = 8; st >= 1; st >>= 1) {
        if (ty < st) {
#pragma unroll
            for (int j = 0; j < 8; j++) {
                float2 a = red[ty * DD + c0 + j];
                float2 b = red[(ty + st) * DD + c0 + j];
                red[ty * DD + c0 + j] = make_float2(a.x + b.x, a.y + b.y);
            }
        }
        __syncthreads();
    }
    if (tid < DD) {
        float2 v = red[tid];
        atomicAdd(&s1[tid], v.x);
        atomicAdd(&s2[tid], v.y);
    }
}

// ---------------- BN finalize+apply (+optional packed-bf16 z emit) ----------------
__global__ __launch_bounds__(256) void k_bnapply(float* __restrict__ hout,
                                                 const float* __restrict__ s1, const float* __restrict__ s2,
                                                 const float* __restrict__ gamma, const float* __restrict__ beta,
                                                 unsigned* __restrict__ zb_out, int relu) {
    int gid = blockIdx.x * blockDim.x + threadIdx.x;
    if (gid >= NN * 32) return;
    int i = gid >> 5, q = gid & 31;
    int c = q * 4;
    // per-thread BN coefficients from global stats (tiny, L2-hit)
    float4 m4 = *(const float4*)(s1 + c);
    float4 q4 = *(const float4*)(s2 + c);
    float4 g4 = *(const float4*)(gamma + c);
    float4 be4 = *(const float4*)(beta + c);
    float A[4], B[4];
    {
        float m[4] = {m4.x, m4.y, m4.z, m4.w};
        float s[4] = {q4.x, q4.y, q4.z, q4.w};
        float g[4] = {g4.x, g4.y, g4.z, g4.w};
        float bb[4] = {be4.x, be4.y, be4.z, be4.w};
#pragma unroll
        for (int j = 0; j < 4; j++) {
            float mean = m[j] * (1.0f / NN);
            float var = s[j] * (1.0f / NN) - mean * mean;
            float a = g[j] * rsqrtf(var + 1e-5f);
            A[j] = a;
            B[j] = bb[j] - mean * a;
        }
    }
    float4* p = (float4*)(hout + (size_t)i * ZCOLS + c);
    float4 v = *p;
    v.x = v.x * A[0] + B[0];
    v.y = v.y * A[1] + B[1];
    v.z = v.z * A[2] + B[2];
    v.w = v.w * A[3] + B[3];
    if (relu) {
        v.x = fmaxf(v.x, 0.f); v.y = fmaxf(v.y, 0.f);
        v.z = fmaxf(v.z, 0.f); v.w = fmaxf(v.w, 0.f);
    }
    *p = v;
    if (zb_out) {
        uint2 w;
        w.x = pack_bf16(v.x, v.y);
        w.y = pack_bf16(v.z, v.w);
        *(uint2*)(zb_out + (size_t)i * 64 + 2 * q) = w;
    }
}

// ---------------- graph pooling (batch is sorted) ----------------
__global__ __launch_bounds__(256) void k_pool(const float* __restrict__ zc, const int* __restrict__ batch,
                                              float* __restrict__ g) {
    const int gr = blockIdx.x;
    int lo = 0, hi = NN;
    while (lo < hi) { int mid = (lo + hi) >> 1; if (batch[mid] < gr) lo = mid + 1; else hi = mid; }
    const int start = lo;
    hi = NN;
    while (lo < hi) { int mid = (lo + hi) >> 1; if (batch[mid] < gr + 1) lo = mid + 1; else hi = mid; }
    const int end = lo;

    const int tid = threadIdx.x;
    const int h = tid >> 7, c = tid & 127;
    float a0 = 0.f, a1 = 0.f, a2 = 0.f;
    for (int r = start + h; r < end; r += 2) {
        const float* row = zc + (size_t)r * ZCOLS;
        a0 += row[c];
        a1 += row[c + DD];
        a2 += row[c + 2 * DD];
    }
    __shared__ float red[3][256];
    red[0][tid] = a0; red[1][tid] = a1; red[2][tid] = a2;
    __syncthreads();
    if (tid < 128) {
        float* gp = g + (size_t)gr * ZCOLS;
        gp[c] = red[0][tid] + red[0][tid + 128];
        gp[c + DD] = red[1][tid] + red[1][tid + 128];
        gp[c + 2 * DD] = red[2][tid] + red[2][tid + 128];
    }
}

extern "C" void kernel_launch(void* const* d_in, const int* in_sizes, int n_in,
                              void* d_out, int out_size, void* d_ws, size_t ws_size,
                              hipStream_t stream) {
    const float* x = (const float*)d_in[0];
    const int* ei = (const int*)d_in[1];
    const int* batch = (const int*)d_in[2];
    const float* W1 = (const float*)d_in[3];
    const float* b1 = (const float*)d_in[4];
    const float* W2 = (const float*)d_in[5];
    const float* b2 = (const float*)d_in[6];
    const float* gamma = (const float*)d_in[7];
    const float* beta = (const float*)d_in[8];
    float* out = (float*)d_out;

    const int* esrc = ei;        // edge_index[0]
    const int* edst = ei + NE;   // edge_index[1]

    int* cnt = (int*)d_ws;            // N
    int* off = cnt + NN;              // N+1
    int* cur = off + NN + 1;          // N
    int* ss = cur + NN;               // E
    float* st = (float*)(ss + NE);    // 3 layers x 2 x 128 stats
    // packed-bf16 z double buffer (256B aligned)
    uintptr_t zbase = (uintptr_t)(st + 6 * DD);
    zbase = (zbase + 255) & ~(uintptr_t)255;
    unsigned* bufA = (unsigned*)zbase;
    unsigned* bufB = bufA + (size_t)NN * 64;
    size_t need = (size_t)((char*)(bufB + (size_t)NN * 64) - (char*)d_ws);
    const int use_bf16 = (ws_size >= need);

    hipMemsetAsync(cnt, 0, NN * sizeof(int), stream);
    hipMemsetAsync(st, 0, 6 * DD * sizeof(float), stream);
    k_hist<<<2048, 256, 0, stream>>>(edst, cnt);
    k_scan<<<1, 1024, 0, stream>>>(cnt, off, cur);
    k_scatter<<<2048, 256, 0, stream>>>(esrc, edst, cur, ss);
    if (use_bf16) k_xcast<<<(NN * 64 + 255) / 256, 256, 0, stream>>>(x, bufA);

    float* gout = out + (size_t)NN * ZCOLS;
    for (int l = 0; l < 3; l++) {
        float* s1 = st + l * 2 * DD;
        float* s2 = s1 + DD;
        // bf16 input buffer for this layer: l0<-bufA(x), l1<-bufB, l2<-bufA
        const unsigned* zb = !use_bf16 ? nullptr : (l == 1 ? bufB : bufA);
        unsigned* zb_out = !use_bf16 ? nullptr : (l == 0 ? bufB : (l == 1 ? bufA : nullptr));
        const float* zf = (l == 0) ? x : out + (l - 1) * DD;
        int zs = (l == 0) ? DD : ZCOLS;
        k_layer<<<(NN + TM - 1) / TM, 256, 0, stream>>>(
            zb, zf, zs, off, ss, W1 + l * DD * DD, b1 + l * DD, W2 + l * DD * DD, b2 + l * DD,
            out + l * DD, s1, s2);
        k_bnapply<<<(NN * 32 + 255) / 256, 256, 0, stream>>>(
            out + l * DD, s1, s2, gamma + l * DD, beta + l * DD, zb_out, (l < 2) ? 1 : 0);
    }
    k_pool<<<NG, 256, 0, stream>>>(out, batch, gout);
}